// Round 6
// baseline (72.448 us; speedup 1.0000x reference)
//
#include <hip/hip_runtime.h>
#include <hip/hip_bf16.h>

#define TT   256
#define BB   8
#define SS   256
#define DD   512
#define C2LOG2E 2.8853900817779268f   // 2*log2(e)
#define LOG2E   1.4426950408889634f

typedef __attribute__((ext_vector_type(8))) short bf16x8;
typedef __attribute__((ext_vector_type(4))) float f32x4;

__device__ __forceinline__ unsigned short f2bf(float f) {
    unsigned u = __builtin_bit_cast(unsigned, f);
    u += 0x7FFFu + ((u >> 16) & 1u);
    return (unsigned short)(u >> 16);
}
__device__ __forceinline__ float bf2f(unsigned short h) {
    unsigned u = (unsigned)h << 16;
    return __builtin_bit_cast(float, u);
}

// ---------------------------------------------------------------------------
// MFMA projection GEMMs, split-bf16 (hi/lo, 3 terms). 512 blocks, XCD-pinned.
// Both outputs are row-major (row = b*256 + t|s, col = k):
//   z=0: eq [b*256+t][k] = exp2(c * qp)
//   z=1: ekR[b*256+s][k] = exp2(c * kp)
// ---------------------------------------------------------------------------
#define LDK 72
__global__ __launch_bounds__(256) void gemm_mfma(const float* __restrict__ query,
                                                 const float* __restrict__ keys,
                                                 const float* __restrict__ Wa,
                                                 float* __restrict__ eq,
                                                 float* __restrict__ ekR) {
    __shared__ __align__(16) unsigned char smem[4 * 64 * LDK * 2];  // 36 KB
    unsigned short* sAh = (unsigned short*)smem;
    unsigned short* sAl = sAh + 64 * LDK;
    unsigned short* sBh = sAl + 64 * LDK;
    unsigned short* sBl = sBh + 64 * LDK;

    const int idx = blockIdx.x;
    const int b   = idx & 7;
    const int r2  = idx >> 3;
    const int q   = r2 & 3;
    const int x   = (r2 >> 2) & 7;
    const int z   = r2 >> 5;
    const bool isQ = (z == 0);

    const float* A  = isQ ? query : keys;
    const int strideR = isQ ? BB * DD : DD;
    const int strideB = isQ ? DD : SS * DD;
    const float* Bsrc = Wa + (isQ ? 0 : DD);
    float* dst = isQ ? eq : ekR;

    const int tileN = x * 64;
    const int tid = threadIdx.x;
    const int rb  = tid >> 4;
    const int c4  = tid & 15;

    const float* arow0 = A + (size_t)b * strideB + (size_t)(q * 64) * strideR;
    const float* brow0 = Bsrc + (size_t)tileN * (2 * DD);

    float4 av[4], bv[4];
    #pragma unroll
    for (int i = 0; i < 4; ++i) {
        av[i] = *(const float4*)(arow0 + (size_t)(rb + 16*i) * strideR + c4 * 4);
        bv[i] = *(const float4*)(brow0 + (size_t)(rb + 16*i) * (2*DD) + c4 * 4);
    }

    const int w    = tid >> 6;
    const int lane = tid & 63;
    const int wm   = (w >> 1) * 32;
    const int wn   = (w & 1) * 32;
    const int r16  = lane & 15;
    const int k8   = (lane >> 4) * 8;

    f32x4 acc[2][2] = {};

    for (int kb = 0; kb < DD; kb += 64) {
        __syncthreads();
        #pragma unroll
        for (int i = 0; i < 4; ++i) {
            const int row = rb + 16 * i;
            float4 a = av[i], bq = bv[i];
            ushort4 ah, al, bh, bl;
            ah.x = f2bf(a.x); al.x = f2bf(a.x - bf2f(ah.x));
            ah.y = f2bf(a.y); al.y = f2bf(a.y - bf2f(ah.y));
            ah.z = f2bf(a.z); al.z = f2bf(a.z - bf2f(ah.z));
            ah.w = f2bf(a.w); al.w = f2bf(a.w - bf2f(ah.w));
            bh.x = f2bf(bq.x); bl.x = f2bf(bq.x - bf2f(bh.x));
            bh.y = f2bf(bq.y); bl.y = f2bf(bq.y - bf2f(bh.y));
            bh.z = f2bf(bq.z); bl.z = f2bf(bq.z - bf2f(bh.z));
            bh.w = f2bf(bq.w); bl.w = f2bf(bq.w - bf2f(bh.w));
            *(ushort4*)(sAh + row * LDK + c4 * 4) = ah;
            *(ushort4*)(sAl + row * LDK + c4 * 4) = al;
            *(ushort4*)(sBh + row * LDK + c4 * 4) = bh;
            *(ushort4*)(sBl + row * LDK + c4 * 4) = bl;
        }
        __syncthreads();
        if (kb + 64 < DD) {
            #pragma unroll
            for (int i = 0; i < 4; ++i) {
                av[i] = *(const float4*)(arow0 + (size_t)(rb + 16*i) * strideR + kb + 64 + c4 * 4);
                bv[i] = *(const float4*)(brow0 + (size_t)(rb + 16*i) * (2*DD) + kb + 64 + c4 * 4);
            }
        }
        #pragma unroll
        for (int ks = 0; ks < 2; ++ks) {
            const int ko = ks * 32 + k8;
            bf16x8 a_h[2], a_l[2], b_h[2], b_l[2];
            #pragma unroll
            for (int mt = 0; mt < 2; ++mt) {
                a_h[mt] = *(const bf16x8*)(sAh + (wm + mt*16 + r16) * LDK + ko);
                a_l[mt] = *(const bf16x8*)(sAl + (wm + mt*16 + r16) * LDK + ko);
            }
            #pragma unroll
            for (int nt = 0; nt < 2; ++nt) {
                b_h[nt] = *(const bf16x8*)(sBh + (wn + nt*16 + r16) * LDK + ko);
                b_l[nt] = *(const bf16x8*)(sBl + (wn + nt*16 + r16) * LDK + ko);
            }
            #pragma unroll
            for (int mt = 0; mt < 2; ++mt)
                #pragma unroll
                for (int nt = 0; nt < 2; ++nt) {
                    acc[mt][nt] = __builtin_amdgcn_mfma_f32_16x16x32_bf16(a_h[mt], b_h[nt], acc[mt][nt], 0, 0, 0);
                    acc[mt][nt] = __builtin_amdgcn_mfma_f32_16x16x32_bf16(a_h[mt], b_l[nt], acc[mt][nt], 0, 0, 0);
                    acc[mt][nt] = __builtin_amdgcn_mfma_f32_16x16x32_bf16(a_l[mt], b_h[nt], acc[mt][nt], 0, 0, 0);
                }
        }
    }

    // Unified epilogue: C/D layout col = lane&15, row = (lane>>4)*4 + reg
    const int crow = (lane >> 4) * 4;
    #pragma unroll
    for (int mt = 0; mt < 2; ++mt)
        #pragma unroll
        for (int nt = 0; nt < 2; ++nt)
            #pragma unroll
            for (int i = 0; i < 4; ++i) {
                const int m = b * 256 + q * 64 + wm + mt*16 + crow + i;
                const int n = tileN + wn + nt*16 + r16;
                dst[(size_t)m * DD + n] = __builtin_amdgcn_exp2f(acc[mt][nt][i] * C2LOG2E);
            }
}

// ---------------------------------------------------------------------------
// Fused attention. 512 blocks x 1024 threads (16 waves), XCD-pinned.
// Phase 1 (wave = kq x sq): partial weights with 4-way rcp batching:
//   sum_i vb_i/y_i (y_i = 1+eq_i*ek_i) = (n01*d23 + n23*d01) * rcp(d01*d23)
//   -> 14 VALU + 1 rcp per 4 k (vs 8 VALU + 4 rcp) — trans-pipe /4.
// Phase 2 (wave = t x sq): softmax distributed over all 16 waves.
// ekR is row-major [b][s][k] so lane's k-run is a contiguous dwordx4 load.
// ---------------------------------------------------------------------------
__global__ __launch_bounds__(1024, 8) void attn_fused(const float* __restrict__ eq,
                                                      const float* __restrict__ ekR,
                                                      const float* __restrict__ va,
                                                      const float* __restrict__ values,
                                                      float* __restrict__ out) {
    __shared__ __align__(16) float eq_s[4][512];     // 8 KB
    __shared__ __align__(16) float vb_s[512];        // 2 KB
    __shared__ __align__(16) float wacc[4][4][256];  // [t][kq][s] 16 KB
    __shared__ __align__(16) float w_s[4][256];      // 4 KB
    __shared__ float red_m[4][4];                    // [sq][t]
    __shared__ float red_s[4][4];

    const int tid  = threadIdx.x;
    const int lane = tid & 63;
    const int w    = tid >> 6;          // 0..15
    const int kq   = w & 3;             // phase1: k-quarter | phase2: t
    const int sq   = w >> 2;            // s-quarter
    const int idx  = blockIdx.x;
    const int b    = idx & 7;           // XCD pin
    const int t0   = (idx >> 3) * 4;

    if (tid < 512) {
        const float4* qsrc = (const float4*)(eq + (size_t)(b * TT + t0) * DD);
        ((float4*)&eq_s[0][0])[tid] = qsrc[tid];
    } else if (tid < 640) {
        const int i = tid - 512;
        float4 v = ((const float4*)va)[i];
        ((float4*)vb_s)[i] = make_float4(-2.f*v.x, -2.f*v.y, -2.f*v.z, -2.f*v.w);
    }
    __syncthreads();

    const int kbase = kq * 128;
    const int s     = sq * 64 + lane;
    const float* ekp = ekR + (size_t)(b * SS + s) * DD + kbase;
    const float4* eqr0 = (const float4*)&eq_s[0][kbase];
    const float4* eqr1 = (const float4*)&eq_s[1][kbase];
    const float4* eqr2 = (const float4*)&eq_s[2][kbase];
    const float4* eqr3 = (const float4*)&eq_s[3][kbase];
    const float4* vbr  = (const float4*)&vb_s[kbase];

    float acc0 = 0.f, acc1 = 0.f, acc2 = 0.f, acc3 = 0.f;

    #pragma unroll 4
    for (int kb = 0; kb < 128; kb += 4) {
        float4 ek = *(const float4*)(ekp + kb);
        float4 vb = vbr[kb >> 2];
        float4 e0 = eqr0[kb >> 2];
        float4 e1 = eqr1[kb >> 2];
        float4 e2 = eqr2[kb >> 2];
        float4 e3 = eqr3[kb >> 2];
#define GSTEP(EQ, ACC)                                                         \
        {                                                                      \
            float y0 = fmaf(EQ.x, ek.x, 1.0f);                                 \
            float y1 = fmaf(EQ.y, ek.y, 1.0f);                                 \
            float y2 = fmaf(EQ.z, ek.z, 1.0f);                                 \
            float y3 = fmaf(EQ.w, ek.w, 1.0f);                                 \
            float d01 = y0 * y1, d23 = y2 * y3;                                \
            float n01 = fmaf(vb.x, y1, vb.y * y0);                             \
            float n23 = fmaf(vb.z, y3, vb.w * y2);                             \
            float num = fmaf(n01, d23, n23 * d01);                             \
            ACC = fmaf(num, __builtin_amdgcn_rcpf(d01 * d23), ACC);            \
        }
        GSTEP(e0, acc0)
        GSTEP(e1, acc1)
        GSTEP(e2, acc2)
        GSTEP(e3, acc3)
#undef GSTEP
    }

    wacc[0][kq][s] = acc0;
    wacc[1][kq][s] = acc1;
    wacc[2][kq][s] = acc2;
    wacc[3][kq][s] = acc3;
    __syncthreads();

    // Phase 2: wave (t = kq, sq) finishes softmax for (t, s-quarter)
    const int t = kq;
    float wt = (wacc[t][0][s] + wacc[t][1][s]) + (wacc[t][2][s] + wacc[t][3][s]);
    {
        float m = wt;
        #pragma unroll
        for (int off = 32; off > 0; off >>= 1) m = fmaxf(m, __shfl_xor(m, off));
        if (lane == 0) red_m[sq][t] = m;
    }
    __syncthreads();
    float M = fmaxf(fmaxf(red_m[0][t], red_m[1][t]),
                    fmaxf(red_m[2][t], red_m[3][t]));
    float p = __builtin_amdgcn_exp2f((wt - M) * LOG2E);
    {
        float sm = p;
        #pragma unroll
        for (int off = 32; off > 0; off >>= 1) sm += __shfl_xor(sm, off);
        if (lane == 0) red_s[sq][t] = sm;
    }
    __syncthreads();
    {
        float inv = __builtin_amdgcn_rcpf((red_s[0][t] + red_s[1][t]) +
                                          (red_s[2][t] + red_s[3][t]));
        float sc = p * inv;
        out[(size_t)(b * TT + t0 + t) * SS + s] = sc;
        w_s[t][s] = sc;
    }
    __syncthreads();

    // ctx: v-column = tid&511, t-pair = tid>>9
    const int v  = tid & 511;
    const int th = tid >> 9;
    const float* vcol = values + (size_t)b * SS * DD + v;
    const float4* wr0 = (const float4*)&w_s[th * 2][0];
    const float4* wr1 = (const float4*)&w_s[th * 2 + 1][0];
    float c0 = 0.f, c1 = 0.f;
    #pragma unroll 4
    for (int ss = 0; ss < SS; ss += 4) {
        float4 w0 = wr0[ss >> 2];
        float4 w1 = wr1[ss >> 2];
        float v0 = vcol[(size_t)(ss + 0) * DD];
        float v1 = vcol[(size_t)(ss + 1) * DD];
        float v2 = vcol[(size_t)(ss + 2) * DD];
        float v3 = vcol[(size_t)(ss + 3) * DD];
        c0 = fmaf(w0.x, v0, c0); c1 = fmaf(w1.x, v0, c1);
        c0 = fmaf(w0.y, v1, c0); c1 = fmaf(w1.y, v1, c1);
        c0 = fmaf(w0.z, v2, c0); c1 = fmaf(w1.z, v2, c1);
        c0 = fmaf(w0.w, v3, c0); c1 = fmaf(w1.w, v3, c1);
    }
    float* octx = out + (size_t)BB * TT * SS + (size_t)(b * TT + t0 + th * 2) * DD + v;
    octx[0]  = c0;
    octx[DD] = c1;
}

// ---------------------------------------------------------------------------
extern "C" void kernel_launch(void* const* d_in, const int* in_sizes, int n_in,
                              void* d_out, int out_size, void* d_ws, size_t ws_size,
                              hipStream_t stream) {
    const float* query  = (const float*)d_in[0];
    const float* keys   = (const float*)d_in[1];
    const float* values = (const float*)d_in[2];
    const float* Wa     = (const float*)d_in[3];
    const float* va     = (const float*)d_in[4];
    float* out = (float*)d_out;

    float* eq  = (float*)d_ws;                    // 2048 x 512 f32 = 4 MB
    float* ekR = eq + (size_t)BB * TT * DD;       // 2048 x 512 f32 = 4 MB

    gemm_mfma<<<512, 256, 0, stream>>>(query, keys, Wa, eq, ekR);
    attn_fused<<<512, 1024, 0, stream>>>(eq, ekR, va, values, out);
}

// Round 7
// 64.366 us; speedup vs baseline: 1.1256x; 1.1256x over previous
//
#include <hip/hip_runtime.h>
#include <hip/hip_bf16.h>

#define TT   256
#define BB   8
#define SS   256
#define DD   512
#define C2LOG2E 2.8853900817779268f   // 2*log2(e)
#define LOG2E   1.4426950408889634f

typedef __attribute__((ext_vector_type(8))) short bf16x8;
typedef __attribute__((ext_vector_type(4))) float f32x4;

__device__ __forceinline__ unsigned short f2bf(float f) {
    unsigned u = __builtin_bit_cast(unsigned, f);
    u += 0x7FFFu + ((u >> 16) & 1u);
    return (unsigned short)(u >> 16);
}
__device__ __forceinline__ float bf2f(unsigned short h) {
    unsigned u = (unsigned)h << 16;
    return __builtin_bit_cast(float, u);
}

// ---------------------------------------------------------------------------
// MFMA projection GEMMs, split-bf16 (hi/lo). 512 blocks, XCD-pinned.
//   z=0: eq [b*256+t][k] = exp2(c*qp)   row-major
//   z=1: ekT[b][k][s]    = exp2(c*kp)   column-major (transposed via LDS)
// ---------------------------------------------------------------------------
#define LDK 72
__global__ __launch_bounds__(256) void gemm_mfma(const float* __restrict__ query,
                                                 const float* __restrict__ keys,
                                                 const float* __restrict__ Wa,
                                                 float* __restrict__ eq,
                                                 float* __restrict__ ekT) {
    __shared__ __align__(16) unsigned char smem[4 * 64 * LDK * 2];  // 36 KB
    unsigned short* sAh = (unsigned short*)smem;
    unsigned short* sAl = sAh + 64 * LDK;
    unsigned short* sBh = sAl + 64 * LDK;
    unsigned short* sBl = sBh + 64 * LDK;
    float* Cst = (float*)smem;                // reused for z=1 transpose

    const int idx = blockIdx.x;
    const int b   = idx & 7;
    const int r2  = idx >> 3;
    const int q   = r2 & 3;
    const int x   = (r2 >> 2) & 7;
    const int z   = r2 >> 5;
    const bool isQ = (z == 0);

    const float* A  = isQ ? query : keys;
    const int strideR = isQ ? BB * DD : DD;
    const int strideB = isQ ? DD : SS * DD;
    const float* Bsrc = Wa + (isQ ? 0 : DD);

    const int tileN = x * 64;
    const int tid = threadIdx.x;
    const int rb  = tid >> 4;
    const int c4  = tid & 15;

    const float* arow0 = A + (size_t)b * strideB + (size_t)(q * 64) * strideR;
    const float* brow0 = Bsrc + (size_t)tileN * (2 * DD);

    float4 av[4], bv[4];
    #pragma unroll
    for (int i = 0; i < 4; ++i) {
        av[i] = *(const float4*)(arow0 + (size_t)(rb + 16*i) * strideR + c4 * 4);
        bv[i] = *(const float4*)(brow0 + (size_t)(rb + 16*i) * (2*DD) + c4 * 4);
    }

    const int w    = tid >> 6;
    const int lane = tid & 63;
    const int wm   = (w >> 1) * 32;
    const int wn   = (w & 1) * 32;
    const int r16  = lane & 15;
    const int k8   = (lane >> 4) * 8;

    f32x4 acc[2][2] = {};

    for (int kb = 0; kb < DD; kb += 64) {
        __syncthreads();
        #pragma unroll
        for (int i = 0; i < 4; ++i) {
            const int row = rb + 16 * i;
            float4 a = av[i], bq = bv[i];
            ushort4 ah, al, bh, bl;
            ah.x = f2bf(a.x); al.x = f2bf(a.x - bf2f(ah.x));
            ah.y = f2bf(a.y); al.y = f2bf(a.y - bf2f(ah.y));
            ah.z = f2bf(a.z); al.z = f2bf(a.z - bf2f(ah.z));
            ah.w = f2bf(a.w); al.w = f2bf(a.w - bf2f(ah.w));
            bh.x = f2bf(bq.x); bl.x = f2bf(bq.x - bf2f(bh.x));
            bh.y = f2bf(bq.y); bl.y = f2bf(bq.y - bf2f(bh.y));
            bh.z = f2bf(bq.z); bl.z = f2bf(bq.z - bf2f(bh.z));
            bh.w = f2bf(bq.w); bl.w = f2bf(bq.w - bf2f(bh.w));
            *(ushort4*)(sAh + row * LDK + c4 * 4) = ah;
            *(ushort4*)(sAl + row * LDK + c4 * 4) = al;
            *(ushort4*)(sBh + row * LDK + c4 * 4) = bh;
            *(ushort4*)(sBl + row * LDK + c4 * 4) = bl;
        }
        __syncthreads();
        if (kb + 64 < DD) {
            #pragma unroll
            for (int i = 0; i < 4; ++i) {
                av[i] = *(const float4*)(arow0 + (size_t)(rb + 16*i) * strideR + kb + 64 + c4 * 4);
                bv[i] = *(const float4*)(brow0 + (size_t)(rb + 16*i) * (2*DD) + kb + 64 + c4 * 4);
            }
        }
        #pragma unroll
        for (int ks = 0; ks < 2; ++ks) {
            const int ko = ks * 32 + k8;
            bf16x8 a_h[2], a_l[2], b_h[2], b_l[2];
            #pragma unroll
            for (int mt = 0; mt < 2; ++mt) {
                a_h[mt] = *(const bf16x8*)(sAh + (wm + mt*16 + r16) * LDK + ko);
                a_l[mt] = *(const bf16x8*)(sAl + (wm + mt*16 + r16) * LDK + ko);
            }
            #pragma unroll
            for (int nt = 0; nt < 2; ++nt) {
                b_h[nt] = *(const bf16x8*)(sBh + (wn + nt*16 + r16) * LDK + ko);
                b_l[nt] = *(const bf16x8*)(sBl + (wn + nt*16 + r16) * LDK + ko);
            }
            #pragma unroll
            for (int mt = 0; mt < 2; ++mt)
                #pragma unroll
                for (int nt = 0; nt < 2; ++nt) {
                    acc[mt][nt] = __builtin_amdgcn_mfma_f32_16x16x32_bf16(a_h[mt], b_h[nt], acc[mt][nt], 0, 0, 0);
                    acc[mt][nt] = __builtin_amdgcn_mfma_f32_16x16x32_bf16(a_h[mt], b_l[nt], acc[mt][nt], 0, 0, 0);
                    acc[mt][nt] = __builtin_amdgcn_mfma_f32_16x16x32_bf16(a_l[mt], b_h[nt], acc[mt][nt], 0, 0, 0);
                }
        }
    }

    const int crow = (lane >> 4) * 4;
    if (isQ) {
        #pragma unroll
        for (int mt = 0; mt < 2; ++mt)
            #pragma unroll
            for (int nt = 0; nt < 2; ++nt)
                #pragma unroll
                for (int i = 0; i < 4; ++i) {
                    const int m = b * 256 + q * 64 + wm + mt*16 + crow + i;
                    const int n = tileN + wn + nt*16 + r16;
                    eq[(size_t)m * DD + n] = __builtin_amdgcn_exp2f(acc[mt][nt][i] * C2LOG2E);
                }
    } else {
        __syncthreads();
        #pragma unroll
        for (int mt = 0; mt < 2; ++mt)
            #pragma unroll
            for (int nt = 0; nt < 2; ++nt)
                #pragma unroll
                for (int i = 0; i < 4; ++i)
                    Cst[(wm + mt*16 + crow + i) * 69 + wn + nt*16 + r16] =
                        __builtin_amdgcn_exp2f(acc[mt][nt][i] * C2LOG2E);
        __syncthreads();
        // rows of Cst = s (local), cols = k (local); store ekT[b][k][s]
        const int n  = tid & 63;       // local k
        const int sg = tid >> 6;       // s-quarter of the 64-row tile
        float* dstp = ekT + (size_t)b * DD * SS + (size_t)(tileN + n) * SS + q * 64 + sg * 16;
        #pragma unroll
        for (int j4 = 0; j4 < 4; ++j4) {
            float4 o;
            o.x = Cst[(sg*16 + j4*4 + 0) * 69 + n];
            o.y = Cst[(sg*16 + j4*4 + 1) * 69 + n];
            o.z = Cst[(sg*16 + j4*4 + 2) * 69 + n];
            o.w = Cst[(sg*16 + j4*4 + 3) * 69 + n];
            *(float4*)(dstp + j4 * 4) = o;
        }
    }
}

// ---------------------------------------------------------------------------
// Fused attention. 512 blocks x 512 threads (8 waves), XCD-pinned.
// Block = (b, 4 t-rows). Wave w owns k-chunk [w*64, w*64+64); lane owns
// s = 4*lane..4*lane+3 (one dwordx4 of ekT per k, coalesced 1KB/wave).
// eq/va are read via threadIdx-independent addresses -> SMEM scalar loads.
// 4-way k-batched rcp: sum_i va_i/y_i = (n01*d23+n23*d01)*rcp(d01*d23),
// y = 1 + eq*ek; final weight = -2 * sum  (+const dropped by softmax).
// ---------------------------------------------------------------------------
__global__ __launch_bounds__(512, 4) void attn_fused(const float* __restrict__ eq,
                                                     const float* __restrict__ ekT,
                                                     const float* __restrict__ va,
                                                     const float* __restrict__ values,
                                                     float* __restrict__ out) {
    __shared__ __align__(16) float wacc[8][4][256];  // 32 KB [kchunk][t][s]
    __shared__ __align__(16) float w_s[4][256];      // 4 KB
    __shared__ float red_m[2][4];                    // [s-half][t]
    __shared__ float red_s[2][4];

    const int tid  = threadIdx.x;
    const int lane = tid & 63;
    const int w    = tid >> 6;          // 0..7 k-chunk
    const int idx  = blockIdx.x;
    const int b    = idx & 7;           // XCD pin
    const int t0   = (idx >> 3) * 4;
    const int k0   = w * 64;

    const float* ekp = ekT + ((size_t)b * DD + k0) * SS + lane * 4;
    const float4* qp0 = (const float4*)(eq + (size_t)(b * TT + t0 + 0) * DD + k0);
    const float4* qp1 = (const float4*)(eq + (size_t)(b * TT + t0 + 1) * DD + k0);
    const float4* qp2 = (const float4*)(eq + (size_t)(b * TT + t0 + 2) * DD + k0);
    const float4* qp3 = (const float4*)(eq + (size_t)(b * TT + t0 + 3) * DD + k0);
    const float4* vap = (const float4*)(va + k0);

    float a00=0,a01=0,a02=0,a03=0, a10=0,a11=0,a12=0,a13=0;
    float a20=0,a21=0,a22=0,a23=0, a30=0,a31=0,a32=0,a33=0;

    #pragma unroll 4
    for (int kb = 0; kb < 64; kb += 4) {
        float4 ek0 = *(const float4*)(ekp + 0 * SS);
        float4 ek1 = *(const float4*)(ekp + 1 * SS);
        float4 ek2 = *(const float4*)(ekp + 2 * SS);
        float4 ek3 = *(const float4*)(ekp + 3 * SS);
        ekp += 4 * SS;
        float4 q0 = qp0[kb >> 2];
        float4 q1 = qp1[kb >> 2];
        float4 q2 = qp2[kb >> 2];
        float4 q3 = qp3[kb >> 2];
        float4 v4 = vap[kb >> 2];
#define GS(Q, E0, E1, E2, E3, ACC) {                                           \
        float y0 = fmaf(Q.x, E0, 1.0f);                                        \
        float y1 = fmaf(Q.y, E1, 1.0f);                                        \
        float y2 = fmaf(Q.z, E2, 1.0f);                                        \
        float y3 = fmaf(Q.w, E3, 1.0f);                                        \
        float d01 = y0 * y1, d23 = y2 * y3;                                    \
        float n01 = fmaf(v4.x, y1, v4.y * y0);                                 \
        float n23 = fmaf(v4.z, y3, v4.w * y2);                                 \
        ACC = fmaf(fmaf(n01, d23, n23 * d01),                                  \
                   __builtin_amdgcn_rcpf(d01 * d23), ACC);                     \
    }
        GS(q0, ek0.x, ek1.x, ek2.x, ek3.x, a00)
        GS(q0, ek0.y, ek1.y, ek2.y, ek3.y, a01)
        GS(q0, ek0.z, ek1.z, ek2.z, ek3.z, a02)
        GS(q0, ek0.w, ek1.w, ek2.w, ek3.w, a03)
        GS(q1, ek0.x, ek1.x, ek2.x, ek3.x, a10)
        GS(q1, ek0.y, ek1.y, ek2.y, ek3.y, a11)
        GS(q1, ek0.z, ek1.z, ek2.z, ek3.z, a12)
        GS(q1, ek0.w, ek1.w, ek2.w, ek3.w, a13)
        GS(q2, ek0.x, ek1.x, ek2.x, ek3.x, a20)
        GS(q2, ek0.y, ek1.y, ek2.y, ek3.y, a21)
        GS(q2, ek0.z, ek1.z, ek2.z, ek3.z, a22)
        GS(q2, ek0.w, ek1.w, ek2.w, ek3.w, a23)
        GS(q3, ek0.x, ek1.x, ek2.x, ek3.x, a30)
        GS(q3, ek0.y, ek1.y, ek2.y, ek3.y, a31)
        GS(q3, ek0.z, ek1.z, ek2.z, ek3.z, a32)
        GS(q3, ek0.w, ek1.w, ek2.w, ek3.w, a33)
#undef GS
    }

    *(float4*)&wacc[w][0][lane * 4] = make_float4(a00, a01, a02, a03);
    *(float4*)&wacc[w][1][lane * 4] = make_float4(a10, a11, a12, a13);
    *(float4*)&wacc[w][2][lane * 4] = make_float4(a20, a21, a22, a23);
    *(float4*)&wacc[w][3][lane * 4] = make_float4(a30, a31, a32, a33);
    __syncthreads();

    // Softmax: wave w -> (t = w&3, s-half = w>>2); lane covers s1, s1+64
    const int t  = w & 3;
    const int sh = w >> 2;
    const int s1 = sh * 128 + lane;
    const int s2 = s1 + 64;
    float wt1 = 0.f, wt2 = 0.f;
    #pragma unroll
    for (int c = 0; c < 8; ++c) {
        wt1 += wacc[c][t][s1];
        wt2 += wacc[c][t][s2];
    }
    wt1 *= -2.0f; wt2 *= -2.0f;
    {
        float m = fmaxf(wt1, wt2);
        #pragma unroll
        for (int off = 32; off > 0; off >>= 1) m = fmaxf(m, __shfl_xor(m, off));
        if (lane == 0) red_m[sh][t] = m;
    }
    __syncthreads();
    const float M = fmaxf(red_m[0][t], red_m[1][t]);
    float p1 = __builtin_amdgcn_exp2f((wt1 - M) * LOG2E);
    float p2 = __builtin_amdgcn_exp2f((wt2 - M) * LOG2E);
    {
        float sm = p1 + p2;
        #pragma unroll
        for (int off = 32; off > 0; off >>= 1) sm += __shfl_xor(sm, off);
        if (lane == 0) red_s[sh][t] = sm;
    }
    __syncthreads();
    {
        float inv = __builtin_amdgcn_rcpf(red_s[0][t] + red_s[1][t]);
        float sc1 = p1 * inv, sc2 = p2 * inv;
        float* orow = out + (size_t)(b * TT + t0 + t) * SS;
        orow[s1] = sc1; orow[s2] = sc2;
        w_s[t][s1] = sc1; w_s[t][s2] = sc2;
    }
    __syncthreads();

    // ctx: thread owns column v = tid (512 = DD)
    const float* vcol = values + (size_t)b * SS * DD + tid;
    const float4* wr0 = (const float4*)&w_s[0][0];
    const float4* wr1 = (const float4*)&w_s[1][0];
    const float4* wr2 = (const float4*)&w_s[2][0];
    const float4* wr3 = (const float4*)&w_s[3][0];
    float c0 = 0.f, c1 = 0.f, c2 = 0.f, c3 = 0.f;
    #pragma unroll 4
    for (int s = 0; s < SS; s += 4) {
        float4 w0 = wr0[s >> 2];
        float4 w1 = wr1[s >> 2];
        float4 w2 = wr2[s >> 2];
        float4 w3 = wr3[s >> 2];
        float v0 = vcol[(size_t)(s + 0) * DD];
        float v1 = vcol[(size_t)(s + 1) * DD];
        float v2 = vcol[(size_t)(s + 2) * DD];
        float v3 = vcol[(size_t)(s + 3) * DD];
        c0 = fmaf(w0.x, v0, c0); c1 = fmaf(w1.x, v0, c1);
        c2 = fmaf(w2.x, v0, c2); c3 = fmaf(w3.x, v0, c3);
        c0 = fmaf(w0.y, v1, c0); c1 = fmaf(w1.y, v1, c1);
        c2 = fmaf(w2.y, v1, c2); c3 = fmaf(w3.y, v1, c3);
        c0 = fmaf(w0.z, v2, c0); c1 = fmaf(w1.z, v2, c1);
        c2 = fmaf(w2.z, v2, c2); c3 = fmaf(w3.z, v2, c3);
        c0 = fmaf(w0.w, v3, c0); c1 = fmaf(w1.w, v3, c1);
        c2 = fmaf(w2.w, v3, c2); c3 = fmaf(w3.w, v3, c3);
    }
    float* octx = out + (size_t)BB * TT * SS + (size_t)(b * TT + t0) * DD + tid;
    octx[0 * DD] = c0; octx[1 * DD] = c1;
    octx[2 * DD] = c2; octx[3 * DD] = c3;
}

// ---------------------------------------------------------------------------
extern "C" void kernel_launch(void* const* d_in, const int* in_sizes, int n_in,
                              void* d_out, int out_size, void* d_ws, size_t ws_size,
                              hipStream_t stream) {
    const float* query  = (const float*)d_in[0];
    const float* keys   = (const float*)d_in[1];
    const float* values = (const float*)d_in[2];
    const float* Wa     = (const float*)d_in[3];
    const float* va     = (const float*)d_in[4];
    float* out = (float*)d_out;

    float* eq  = (float*)d_ws;                    // 2048 x 512 f32 = 4 MB
    float* ekT = eq + (size_t)BB * TT * DD;       // 8 x 512 x 256 f32 = 4 MB

    gemm_mfma<<<512, 256, 0, stream>>>(query, keys, Wa, eq, ekT);
    attn_fused<<<512, 512, 0, stream>>>(eq, ekT, va, values, out);
}